// Round 5
// baseline (829.900 us; speedup 1.0000x reference)
//
#include <hip/hip_runtime.h>
#include <stdint.h>

#define B_ 8
#define C_ 256
#define N_ 4096
#define CQK 32
#define VPANEL (C_ * 64)   // f16 elements per 64-key V panel (256 c x 64 j)

typedef __attribute__((ext_vector_type(8))) _Float16 f16x8;
typedef __attribute__((ext_vector_type(4))) float f32x4;

__device__ __forceinline__ unsigned short f2bf_rne(float f) {
  unsigned u = __builtin_bit_cast(unsigned, f);
  u += 0x7FFFu + ((u >> 16) & 1u);
  return (unsigned short)(u >> 16);
}

// keepalive: defeat DCE without cost (rule #17)
__device__ __forceinline__ void keep4(f32x4 v) { asm volatile("" :: "v"(v)); }
__device__ __forceinline__ void keep8(f16x8 v) { keep4(__builtin_bit_cast(f32x4, v)); }

// ---------------------------------------------------------------------------
// Kernel 1: transpose x [b][c][n] fp32 -> xT [b][n][c] fp16 (c contiguous).
// ---------------------------------------------------------------------------
__global__ __launch_bounds__(256) void xpose_kernel(
    const float* __restrict__ x, _Float16* __restrict__ xT)
{
  __shared__ float xs[64 * 129];
  const int t  = threadIdx.x;
  const int blk = blockIdx.x;
  const int nt = blk & 31;          // n-tile (128 px)
  const int ct = (blk >> 5) & 3;    // c-tile (64 ch)
  const int b  = blk >> 7;
  const int c0 = ct * 64, n0 = nt * 128;

  #pragma unroll
  for (int p = 0; p < 8; ++p) {
    int cc = p * 8 + (t >> 5);
    int nn = (t & 31) * 4;
    float4 v = *(const float4*)(x + ((size_t)(b * C_ + c0 + cc)) * N_ + n0 + nn);
    xs[cc * 129 + nn]     = v.x;
    xs[cc * 129 + nn + 1] = v.y;
    xs[cc * 129 + nn + 2] = v.z;
    xs[cc * 129 + nn + 3] = v.w;
  }
  __syncthreads();
  #pragma unroll
  for (int p = 0; p < 4; ++p) {
    int id = p * 256 + t;
    int cchunk = id & 7, n = id >> 3;   // n in [0,128)
    _Float16 h[8];
    #pragma unroll
    for (int j = 0; j < 8; ++j) h[j] = (_Float16)xs[(cchunk * 8 + j) * 129 + n];
    *(f16x8*)(xT + ((size_t)(b * N_) + n0 + n) * C_ + c0 + cchunk * 8) = *(f16x8*)h;
  }
}

// ---------------------------------------------------------------------------
// Kernel 2: convert weights to fp16, concatenated Wcat[320][256].
// ---------------------------------------------------------------------------
__global__ __launch_bounds__(256) void wconv_kernel(
    const float* __restrict__ wq, const float* __restrict__ wk,
    const float* __restrict__ wv, _Float16* __restrict__ wf)
{
  int idx = blockIdx.x * 256 + threadIdx.x;   // 20480 threads x 4 elems
  int e = idx * 4;
  int o = e >> 8, c = e & 255;
  const float* src;
  if (o < 32)      src = wq + o * 256 + c;
  else if (o < 64) src = wk + (o - 32) * 256 + c;
  else             src = wv + (o - 64) * 256 + c;
  float4 v = *(const float4*)src;
  _Float16 h[4] = {(_Float16)v.x, (_Float16)v.y, (_Float16)v.z, (_Float16)v.w};
  *(uint2*)(wf + e) = *(uint2*)h;
}

// ---------------------------------------------------------------------------
// Kernel 3: projection GEMM (fp16 MFMA). q rows pre-scaled by log2(e).
// V written PANEL-MAJOR: [b][jt=64][c=256][j=64] f16.
// ---------------------------------------------------------------------------
__global__ __launch_bounds__(256, 4) void proj_gemm_kernel(
    const _Float16* __restrict__ xT, const _Float16* __restrict__ wf,
    const float* __restrict__ bq, const float* __restrict__ bk,
    const float* __restrict__ bv,
    _Float16* __restrict__ qf, _Float16* __restrict__ kf,
    _Float16* __restrict__ vout)
{
  const int t = threadIdx.x, lane = t & 63;
  const int w = t >> 6;
  const int l15 = lane & 15, q4 = lane >> 4;
  const int blk = blockIdx.x;
  const int otile = blk % 5;          // 0 = q/k, 1..4 = v
  const int nt = blk / 5;             // 256 n-tiles (8 b x 32)
  const int b  = nt >> 5;
  const int n0 = (nt & 31) * 128;
  const int o0w = (w & 1) * 32;
  const int n0w = (w >> 1) * 64;

  f32x4 acc[2][4];
  const f32x4 zf = {0.f, 0.f, 0.f, 0.f};
  #pragma unroll
  for (int a = 0; a < 2; ++a)
    #pragma unroll
    for (int bb = 0; bb < 4; ++bb) acc[a][bb] = zf;

  const _Float16* wbase = wf + (size_t)(otile * 64 + o0w) * 256;
  const _Float16* xbase = xT + ((size_t)(b * N_) + n0 + n0w) * C_;

  #pragma unroll
  for (int kc = 0; kc < 8; ++kc) {
    f16x8 af[2], bfr[4];
    #pragma unroll
    for (int ob = 0; ob < 2; ++ob)
      af[ob] = *(const f16x8*)(wbase + (ob * 16 + l15) * 256 + kc * 32 + q4 * 8);
    #pragma unroll
    for (int nb = 0; nb < 4; ++nb)
      bfr[nb] = *(const f16x8*)(xbase + (nb * 16 + l15) * 256 + kc * 32 + q4 * 8);
    #pragma unroll
    for (int ob = 0; ob < 2; ++ob)
      #pragma unroll
      for (int nb = 0; nb < 4; ++nb)
        acc[ob][nb] = __builtin_amdgcn_mfma_f32_16x16x32_f16(af[ob], bfr[nb], acc[ob][nb], 0, 0, 0);
  }

  if (otile == 0) {
    _Float16* dst = (o0w == 0) ? qf : kf;
    const float* bias = (o0w == 0) ? bq : bk;
    const float qsc = (o0w == 0) ? 1.4426950408889634f : 1.0f;  // log2(e) for q
    #pragma unroll
    for (int ob = 0; ob < 2; ++ob) {
      float4 b4 = *(const float4*)(bias + ob * 16 + q4 * 4);
      #pragma unroll
      for (int nb = 0; nb < 4; ++nb) {
        int pixel = n0 + n0w + nb * 16 + l15;
        _Float16 h[4];
        h[0] = (_Float16)((acc[ob][nb][0] + b4.x) * qsc);
        h[1] = (_Float16)((acc[ob][nb][1] + b4.y) * qsc);
        h[2] = (_Float16)((acc[ob][nb][2] + b4.z) * qsc);
        h[3] = (_Float16)((acc[ob][nb][3] + b4.w) * qsc);
        *(uint2*)(dst + ((size_t)(b * N_) + pixel) * CQK + ob * 16 + q4 * 4) = *(uint2*)h;
      }
    }
  } else {
    int cbase = (otile - 1) * 64 + o0w;
    const int panel = (n0 + n0w) >> 6;       // fixed per (block, wave)
    _Float16* vpan = vout + ((size_t)(b * 64 + panel)) * VPANEL;
    #pragma unroll
    for (int ob = 0; ob < 2; ++ob) {
      float4 b4 = *(const float4*)(bv + cbase + ob * 16 + q4 * 4);
      #pragma unroll
      for (int nb = 0; nb < 4; ++nb) {
        int jj = nb * 16 + l15;              // j within panel, 0..63
        #pragma unroll
        for (int r = 0; r < 4; ++r) {
          int c = cbase + ob * 16 + q4 * 4 + r;
          float bval = (r == 0) ? b4.x : (r == 1) ? b4.y : (r == 2) ? b4.z : b4.w;
          vpan[(size_t)c * 64 + jj] = (_Float16)(acc[ob][nb][r] + bval);
        }
      }
    }
  }
}

// ---------------------------------------------------------------------------
// Kernel 4: fused flash attention + residual -> yout (bf16).
// template<MODE> ABLATION (rule #17 keepalives; probes write garbage into
// yout, which MODE 0 — launched LAST — fully overwrites):
//   MODE 0: full (the real kernel, identical schedule to round 4)
//   MODE 1: PV MFMAs removed (V loads kept alive)       -> PV cost
//   MODE 2: softmax VALU/shfl removed (raw S packed)    -> softmax cost
//   MODE 3: in-loop K/V global loads removed (stale)    -> load-stall cost
//   MODE 4: barriers/waitcnt removed (racy, tolerated)  -> lockstep cost
// ---------------------------------------------------------------------------
#define BAR_PUB() do { \
  if constexpr (MODE != 4) { \
    asm volatile("s_waitcnt lgkmcnt(0)" ::: "memory"); \
    __builtin_amdgcn_sched_barrier(0); \
    __builtin_amdgcn_s_barrier(); \
    asm volatile("" ::: "memory"); \
  } \
} while (0)

#define PV_CONS(RB, VC) do { \
  if constexpr (MODE == 1) { \
    _Pragma("unroll") \
    for (int q_ = 0; q_ < 8; ++q_) keep8(VC[q_]); \
  } else { \
    int4 fl_ = *(const int4*)(flagw + (RB) * 4); \
    if (fl_.x | fl_.y | fl_.z | fl_.w) { \
      _Pragma("unroll") \
      for (int ib = 0; ib < 4; ++ib) { \
        float av_ = alphal[(RB) * 64 + ib * 16 + l15]; \
        _Pragma("unroll") \
        for (int cb = 0; cb < 4; ++cb) \
          _Pragma("unroll") \
          for (int r = 0; r < 4; ++r) acc[cb][ib][r] *= av_; } } \
    __builtin_amdgcn_s_setprio(1); \
    _Pragma("unroll") \
    for (int ks = 0; ks < 2; ++ks) { \
      f16x8 pf_[4]; \
      _Pragma("unroll") \
      for (int ib = 0; ib < 4; ++ib) \
        pf_[ib] = *(const f16x8*)((char*)Plds + (RB) * 9216 + (ib * 16 + l15) * 144 + ks * 64 + q4 * 16); \
      _Pragma("unroll") \
      for (int cb = 0; cb < 4; ++cb) \
        _Pragma("unroll") \
        for (int ib = 0; ib < 4; ++ib) \
          acc[cb][ib] = __builtin_amdgcn_mfma_f32_16x16x32_f16(VC[ks * 4 + cb], pf_[ib], acc[cb][ib], 0, 0, 0); \
    } \
    __builtin_amdgcn_s_setprio(0); \
  } \
} while (0)

#define SMAX_PUB(KC, WB) do { \
  f32x4 sv_[4]; \
  _Pragma("unroll") \
  for (int jb = 0; jb < 4; ++jb) \
    sv_[jb] = __builtin_amdgcn_mfma_f32_16x16x32_f16(KC[jb], qfr, zf, 0, 0, 0); \
  if constexpr (MODE == 2) { \
    /* pack raw S straight to P; no max/exp/sum/shfl/ballot */ \
    char* pb_ = (char*)Plds + (WB) * 9216 + (w * 16 + l15) * 144 + q4 * 8; \
    _Pragma("unroll") \
    for (int jb = 0; jb < 4; ++jb) { \
      _Float16 h_[4] = {(_Float16)sv_[jb][0], (_Float16)sv_[jb][1], \
                        (_Float16)sv_[jb][2], (_Float16)sv_[jb][3]}; \
      *(uint2*)(pb_ + jb * 32) = *(uint2*)h_; } \
    if (q4 == 0) alphal[(WB) * 64 + w * 16 + l15] = 1.0f; \
    if (lane == 0) flagw[(WB) * 4 + w] = 0; \
  } else { \
    float lm_ = sv_[0][0]; \
    _Pragma("unroll") \
    for (int jb = 0; jb < 4; ++jb) \
      lm_ = fmaxf(lm_, fmaxf(fmaxf(sv_[jb][0], sv_[jb][1]), fmaxf(sv_[jb][2], sv_[jb][3]))); \
    lm_ = fmaxf(lm_, __shfl_xor(lm_, 16)); \
    lm_ = fmaxf(lm_, __shfl_xor(lm_, 32)); \
    bool upd_ = lm_ > mold + 8.0f; \
    unsigned long long bal_ = __ballot(upd_);   /* full-wave scope */ \
    float alpha_ = upd_ ? exp2f(mold - lm_) : 1.0f; \
    if (upd_) mold = lm_; \
    float ts_ = 0.f; \
    float p_[4][4]; \
    _Pragma("unroll") \
    for (int jb = 0; jb < 4; ++jb) \
      _Pragma("unroll") \
      for (int r = 0; r < 4; ++r) { p_[jb][r] = exp2f(sv_[jb][r] - mold); ts_ += p_[jb][r]; } \
    ts_ += __shfl_xor(ts_, 16); \
    ts_ += __shfl_xor(ts_, 32); \
    lrun = lrun * alpha_ + ts_; \
    { char* pb_ = (char*)Plds + (WB) * 9216 + (w * 16 + l15) * 144 + q4 * 8; \
      _Pragma("unroll") \
      for (int jb = 0; jb < 4; ++jb) { \
        _Float16 h_[4] = {(_Float16)p_[jb][0], (_Float16)p_[jb][1], \
                          (_Float16)p_[jb][2], (_Float16)p_[jb][3]}; \
        *(uint2*)(pb_ + jb * 32) = *(uint2*)h_; } } \
    if (q4 == 0) alphal[(WB) * 64 + w * 16 + l15] = alpha_; \
    if (lane == 0) flagw[(WB) * 4 + w] = (bal_ != 0ull) ? 1 : 0; \
  } \
} while (0)

#define ATTN_BODY(K, VC, VN, KC, KN) do { \
  if constexpr (MODE != 3) { \
    _Pragma("unroll") \
    for (int ks = 0; ks < 2; ++ks) \
      _Pragma("unroll") \
      for (int cb = 0; cb < 4; ++cb) \
        VN[ks * 4 + cb] = *(const f16x8*)(vpan + cb * 1024 + ks * 32); \
    vpan += VPANEL; \
    { const _Float16* knp_ = kbase + (size_t)((((K) + 2) & 63) * 64) * CQK; \
      _Pragma("unroll") \
      for (int jb = 0; jb < 4; ++jb) KN[jb] = *(const f16x8*)(knp_ + jb * 16 * CQK); } \
    if constexpr (MODE == 1) { \
      _Pragma("unroll") \
      for (int q_ = 0; q_ < 8; ++q_) keep8(VN[q_]); \
    } \
  } \
  PV_CONS((K) & 1, VC); \
  SMAX_PUB(KC, ((K) + 1) & 1); \
  BAR_PUB(); \
} while (0)

template <int MODE>
__global__ __launch_bounds__(256, 2) void attn_tpl(
    const float* __restrict__ x, const float* __restrict__ gptr,
    const _Float16* __restrict__ qf, const _Float16* __restrict__ kf,
    const _Float16* __restrict__ vf, unsigned short* __restrict__ yout)
{
  __shared__ __align__(16) char smem[19232];
  _Float16* Plds  = (_Float16*)smem;             // [2][64 rows][144 B]
  float* alphal = (float*)(smem + 18432);        // [2][64]
  int*   flagw  = (int*)(smem + 18944);          // [2][4]
  float* lrowl  = (float*)(smem + 18976);        // [64]

  const int t = threadIdx.x, lane = t & 63;
  const int w = t >> 6;                           // 4 waves
  const int l15 = lane & 15, q4 = lane >> 4;
  const int b  = blockIdx.x & 7;                  // batch == XCD
  const int it = blockIdx.x >> 3;
  const int i0 = it * 64;
  const float gamma = gptr[0];

  const f16x8 qfr = *(const f16x8*)(qf + ((size_t)(b * N_) + i0 + w * 16 + l15) * CQK + q4 * 8);

  const _Float16* kbase = kf + ((size_t)(b * N_) + l15) * CQK + q4 * 8;
  const _Float16* vpan = vf + (size_t)b * (64 * VPANEL)
                            + ((size_t)(w * 64 + l15)) * 64 + q4 * 8;

  f32x4 acc[4][4];   // [cb][ib]: c = w*64+cb*16+q4*4+r, i = ib*16+l15
  const f32x4 zf = {0.f, 0.f, 0.f, 0.f};
  #pragma unroll
  for (int a = 0; a < 4; ++a)
    #pragma unroll
    for (int bb = 0; bb < 4; ++bb) acc[a][bb] = zf;

  float mold = -1e30f, lrun = 0.f;

  f16x8 ka[4], kb[4], va[8], vb[8];
  #pragma unroll
  for (int jb = 0; jb < 4; ++jb) ka[jb] = *(const f16x8*)(kbase + jb * 16 * CQK);
  #pragma unroll
  for (int jb = 0; jb < 4; ++jb) kb[jb] = *(const f16x8*)(kbase + (size_t)(64 * CQK) + jb * 16 * CQK);
  #pragma unroll
  for (int ks = 0; ks < 2; ++ks)
    #pragma unroll
    for (int cb = 0; cb < 4; ++cb)
      va[ks * 4 + cb] = *(const f16x8*)(vpan + cb * 1024 + ks * 32);
  vpan += VPANEL;

  // prologue: publish tile 0
  SMAX_PUB(ka, 0);
  BAR_PUB();

  #pragma unroll 1
  for (int k = 0; k < 62; k += 2) {
    ATTN_BODY(k,     va, vb, kb, ka);
    ATTN_BODY(k + 1, vb, va, ka, kb);
  }
  ATTN_BODY(62, va, vb, kb, ka);
  PV_CONS(1, vb);   // tile 63

  if (q4 == 0) lrowl[w * 16 + l15] = lrun;
  __syncthreads();
  #pragma unroll
  for (int ib = 0; ib < 4; ++ib) {
    float linv = 1.0f / lrowl[ib * 16 + l15];
    int i = i0 + ib * 16 + l15;
    #pragma unroll
    for (int cb = 0; cb < 4; ++cb) {
      #pragma unroll
      for (int r = 0; r < 4; ++r) {
        int c = w * 64 + cb * 16 + q4 * 4 + r;
        size_t off = ((size_t)(b * C_) + c) * N_ + i;
        float o = acc[cb][ib][r] * linv;
        yout[off] = f2bf_rne(fmaf(gamma, o, x[off]));
      }
    }
  }
}

// ---------------------------------------------------------------------------
// Kernel 5: BN statistics from bf16 yout; one block per channel.
// ---------------------------------------------------------------------------
__global__ __launch_bounds__(256) void bnstats_kernel(
    const unsigned short* __restrict__ y, float* __restrict__ meanw, float* __restrict__ rstdw)
{
  const int c = blockIdx.x;
  const int t = threadIdx.x;
  float s1 = 0.f, s2 = 0.f;
  for (int b = 0; b < B_; ++b) {
    const unsigned short* p = y + ((size_t)(b * C_ + c)) * N_;
    #pragma unroll
    for (int r = 0; r < 2; ++r) {
      uint4 u = *(const uint4*)(p + r * 2048 + t * 8);
      unsigned uu[4] = {u.x, u.y, u.z, u.w};
      #pragma unroll
      for (int k = 0; k < 4; ++k) {
        float a = __builtin_bit_cast(float, uu[k] << 16);
        float bb = __builtin_bit_cast(float, uu[k] & 0xFFFF0000u);
        s1 += a + bb;
        s2 += a * a + bb * bb;
      }
    }
  }
  __shared__ float r1[256], r2[256];
  r1[t] = s1; r2[t] = s2;
  __syncthreads();
  for (int s = 128; s > 0; s >>= 1) {
    if (t < s) { r1[t] += r1[t + s]; r2[t] += r2[t + s]; }
    __syncthreads();
  }
  if (t == 0) {
    float mean = r1[0] * (1.0f / 32768.0f);
    float var  = r2[0] * (1.0f / 32768.0f) - mean * mean;
    meanw[c] = mean;
    rstdw[c] = rsqrtf(var + 1e-5f);
  }
}

// ---------------------------------------------------------------------------
// Kernel 6: BN normalize + ReLU: bf16 yout -> fp32 d_out.
// ---------------------------------------------------------------------------
__global__ __launch_bounds__(256) void bnapply_kernel(
    const unsigned short* __restrict__ y, float* __restrict__ out,
    const float* __restrict__ meanw, const float* __restrict__ rstdw,
    const float* __restrict__ bnw, const float* __restrict__ bnb)
{
  size_t idx = (size_t)blockIdx.x * 256 + threadIdx.x;   // 1,048,576 threads
  size_t el = idx * 8;
  int c = (int)((el >> 12) & 255);
  float sc = bnw[c] * rstdw[c];
  float sh = fmaf(-meanw[c], sc, bnb[c]);
  uint4 u = *(const uint4*)(y + el);
  unsigned uu[4] = {u.x, u.y, u.z, u.w};
  float4 o0, o1;
  float v[8];
  #pragma unroll
  for (int k = 0; k < 4; ++k) {
    v[2 * k]     = __builtin_bit_cast(float, uu[k] << 16);
    v[2 * k + 1] = __builtin_bit_cast(float, uu[k] & 0xFFFF0000u);
  }
  o0.x = fmaxf(fmaf(v[0], sc, sh), 0.f);
  o0.y = fmaxf(fmaf(v[1], sc, sh), 0.f);
  o0.z = fmaxf(fmaf(v[2], sc, sh), 0.f);
  o0.w = fmaxf(fmaf(v[3], sc, sh), 0.f);
  o1.x = fmaxf(fmaf(v[4], sc, sh), 0.f);
  o1.y = fmaxf(fmaf(v[5], sc, sh), 0.f);
  o1.z = fmaxf(fmaf(v[6], sc, sh), 0.f);
  o1.w = fmaxf(fmaf(v[7], sc, sh), 0.f);
  *(float4*)(out + el) = o0;
  *(float4*)(out + el + 4) = o1;
}

extern "C" void kernel_launch(void* const* d_in, const int* in_sizes, int n_in,
                              void* d_out, int out_size, void* d_ws, size_t ws_size,
                              hipStream_t stream)
{
  const float* x   = (const float*)d_in[0];
  const float* wq  = (const float*)d_in[1];
  const float* bq  = (const float*)d_in[2];
  const float* wk  = (const float*)d_in[3];
  const float* bk  = (const float*)d_in[4];
  const float* wv  = (const float*)d_in[5];
  const float* bv  = (const float*)d_in[6];
  const float* gm  = (const float*)d_in[7];
  const float* bnw = (const float*)d_in[8];
  const float* bnb = (const float*)d_in[9];
  float* out = (float*)d_out;

  _Float16* xT  = (_Float16*)d_out;
  _Float16* vfp = (_Float16*)((char*)d_out + (size_t)B_ * C_ * N_ * 2);

  char* ws = (char*)d_ws;
  _Float16* qf = (_Float16*)(ws);
  _Float16* kf = (_Float16*)(ws + ((size_t)2 << 20));
  unsigned short* yout = (unsigned short*)(ws + ((size_t)4 << 20));
  _Float16* wf = (_Float16*)(ws + ((size_t)21 << 20));
  float* meanw = (float*)(ws + ((size_t)22 << 20));
  float* rstdw = (float*)(ws + ((size_t)22 << 20) + 4096);

  hipLaunchKernelGGL(xpose_kernel, dim3(1024), dim3(256), 0, stream, x, xT);
  hipLaunchKernelGGL(wconv_kernel, dim3(80), dim3(256), 0, stream, wq, wk, wv, wf);
  hipLaunchKernelGGL(proj_gemm_kernel, dim3(1280), dim3(256), 0, stream,
                     xT, wf, bq, bk, bv, qf, kf, vfp);

  // ---- ablation probes (garbage into yout; overwritten by the real attn) --
  hipLaunchKernelGGL((attn_tpl<1>), dim3(512), dim3(256), 0, stream,
                     x, gm, qf, kf, vfp, yout);   // no PV
  hipLaunchKernelGGL((attn_tpl<2>), dim3(512), dim3(256), 0, stream,
                     x, gm, qf, kf, vfp, yout);   // no softmax
  hipLaunchKernelGGL((attn_tpl<3>), dim3(512), dim3(256), 0, stream,
                     x, gm, qf, kf, vfp, yout);   // no in-loop loads
  hipLaunchKernelGGL((attn_tpl<4>), dim3(512), dim3(256), 0, stream,
                     x, gm, qf, kf, vfp, yout);   // no barriers

  // ---- the real attention (must be LAST of the attn family) --------------
  hipLaunchKernelGGL((attn_tpl<0>), dim3(512), dim3(256), 0, stream,
                     x, gm, qf, kf, vfp, yout);

  hipLaunchKernelGGL(bnstats_kernel, dim3(256), dim3(256), 0, stream,
                     yout, meanw, rstdw);
  hipLaunchKernelGGL(bnapply_kernel, dim3(4096), dim3(256), 0, stream,
                     yout, out, meanw, rstdw, bnw, bnb);
}

// Round 6
// 297.810 us; speedup vs baseline: 2.7867x; 2.7867x over previous
//
#include <hip/hip_runtime.h>
#include <stdint.h>

#define B_ 8
#define C_ 256
#define N_ 4096
#define CQK 32
#define VPANEL (C_ * 64)   // f16 elements per 64-key V panel (256 c x 64 j)

typedef __attribute__((ext_vector_type(8))) _Float16 f16x8;
typedef __attribute__((ext_vector_type(4))) float f32x4;

__device__ __forceinline__ unsigned short f2bf_rne(float f) {
  unsigned u = __builtin_bit_cast(unsigned, f);
  u += 0x7FFFu + ((u >> 16) & 1u);
  return (unsigned short)(u >> 16);
}

// ---------------------------------------------------------------------------
// Kernel 1: transpose x [b][c][n] fp32 -> xT [b][n][c] fp16 (c contiguous).
// ---------------------------------------------------------------------------
__global__ __launch_bounds__(256) void xpose_kernel(
    const float* __restrict__ x, _Float16* __restrict__ xT)
{
  __shared__ float xs[64 * 129];
  const int t  = threadIdx.x;
  const int blk = blockIdx.x;
  const int nt = blk & 31;          // n-tile (128 px)
  const int ct = (blk >> 5) & 3;    // c-tile (64 ch)
  const int b  = blk >> 7;
  const int c0 = ct * 64, n0 = nt * 128;

  #pragma unroll
  for (int p = 0; p < 8; ++p) {
    int cc = p * 8 + (t >> 5);
    int nn = (t & 31) * 4;
    float4 v = *(const float4*)(x + ((size_t)(b * C_ + c0 + cc)) * N_ + n0 + nn);
    xs[cc * 129 + nn]     = v.x;
    xs[cc * 129 + nn + 1] = v.y;
    xs[cc * 129 + nn + 2] = v.z;
    xs[cc * 129 + nn + 3] = v.w;
  }
  __syncthreads();
  #pragma unroll
  for (int p = 0; p < 4; ++p) {
    int id = p * 256 + t;
    int cchunk = id & 7, n = id >> 3;   // n in [0,128)
    _Float16 h[8];
    #pragma unroll
    for (int j = 0; j < 8; ++j) h[j] = (_Float16)xs[(cchunk * 8 + j) * 129 + n];
    *(f16x8*)(xT + ((size_t)(b * N_) + n0 + n) * C_ + c0 + cchunk * 8) = *(f16x8*)h;
  }
}

// ---------------------------------------------------------------------------
// Kernel 2: convert weights to fp16, concatenated Wcat[320][256].
// ---------------------------------------------------------------------------
__global__ __launch_bounds__(256) void wconv_kernel(
    const float* __restrict__ wq, const float* __restrict__ wk,
    const float* __restrict__ wv, _Float16* __restrict__ wf)
{
  int idx = blockIdx.x * 256 + threadIdx.x;   // 20480 threads x 4 elems
  int e = idx * 4;
  int o = e >> 8, c = e & 255;
  const float* src;
  if (o < 32)      src = wq + o * 256 + c;
  else if (o < 64) src = wk + (o - 32) * 256 + c;
  else             src = wv + (o - 64) * 256 + c;
  float4 v = *(const float4*)src;
  _Float16 h[4] = {(_Float16)v.x, (_Float16)v.y, (_Float16)v.z, (_Float16)v.w};
  *(uint2*)(wf + e) = *(uint2*)h;
}

// ---------------------------------------------------------------------------
// Kernel 3: projection GEMM (fp16 MFMA). q rows pre-scaled by log2(e).
// V written PANEL-MAJOR: [b][jt=64][c=256][j=64] f16.
// ---------------------------------------------------------------------------
__global__ __launch_bounds__(256, 4) void proj_gemm_kernel(
    const _Float16* __restrict__ xT, const _Float16* __restrict__ wf,
    const float* __restrict__ bq, const float* __restrict__ bk,
    const float* __restrict__ bv,
    _Float16* __restrict__ qf, _Float16* __restrict__ kf,
    _Float16* __restrict__ vout)
{
  const int t = threadIdx.x, lane = t & 63;
  const int w = t >> 6;
  const int l15 = lane & 15, q4 = lane >> 4;
  const int blk = blockIdx.x;
  const int otile = blk % 5;          // 0 = q/k, 1..4 = v
  const int nt = blk / 5;             // 256 n-tiles (8 b x 32)
  const int b  = nt >> 5;
  const int n0 = (nt & 31) * 128;
  const int o0w = (w & 1) * 32;
  const int n0w = (w >> 1) * 64;

  f32x4 acc[2][4];
  const f32x4 zf = {0.f, 0.f, 0.f, 0.f};
  #pragma unroll
  for (int a = 0; a < 2; ++a)
    #pragma unroll
    for (int bb = 0; bb < 4; ++bb) acc[a][bb] = zf;

  const _Float16* wbase = wf + (size_t)(otile * 64 + o0w) * 256;
  const _Float16* xbase = xT + ((size_t)(b * N_) + n0 + n0w) * C_;

  #pragma unroll
  for (int kc = 0; kc < 8; ++kc) {
    f16x8 af[2], bfr[4];
    #pragma unroll
    for (int ob = 0; ob < 2; ++ob)
      af[ob] = *(const f16x8*)(wbase + (ob * 16 + l15) * 256 + kc * 32 + q4 * 8);
    #pragma unroll
    for (int nb = 0; nb < 4; ++nb)
      bfr[nb] = *(const f16x8*)(xbase + (nb * 16 + l15) * 256 + kc * 32 + q4 * 8);
    #pragma unroll
    for (int ob = 0; ob < 2; ++ob)
      #pragma unroll
      for (int nb = 0; nb < 4; ++nb)
        acc[ob][nb] = __builtin_amdgcn_mfma_f32_16x16x32_f16(af[ob], bfr[nb], acc[ob][nb], 0, 0, 0);
  }

  if (otile == 0) {
    _Float16* dst = (o0w == 0) ? qf : kf;
    const float* bias = (o0w == 0) ? bq : bk;
    const float qsc = (o0w == 0) ? 1.4426950408889634f : 1.0f;  // log2(e) for q
    #pragma unroll
    for (int ob = 0; ob < 2; ++ob) {
      float4 b4 = *(const float4*)(bias + ob * 16 + q4 * 4);
      #pragma unroll
      for (int nb = 0; nb < 4; ++nb) {
        int pixel = n0 + n0w + nb * 16 + l15;
        _Float16 h[4];
        h[0] = (_Float16)((acc[ob][nb][0] + b4.x) * qsc);
        h[1] = (_Float16)((acc[ob][nb][1] + b4.y) * qsc);
        h[2] = (_Float16)((acc[ob][nb][2] + b4.z) * qsc);
        h[3] = (_Float16)((acc[ob][nb][3] + b4.w) * qsc);
        *(uint2*)(dst + ((size_t)(b * N_) + pixel) * CQK + ob * 16 + q4 * 4) = *(uint2*)h;
      }
    }
  } else {
    int cbase = (otile - 1) * 64 + o0w;
    const int panel = (n0 + n0w) >> 6;       // fixed per (block, wave)
    _Float16* vpan = vout + ((size_t)(b * 64 + panel)) * VPANEL;
    #pragma unroll
    for (int ob = 0; ob < 2; ++ob) {
      float4 b4 = *(const float4*)(bv + cbase + ob * 16 + q4 * 4);
      #pragma unroll
      for (int nb = 0; nb < 4; ++nb) {
        int jj = nb * 16 + l15;              // j within panel, 0..63
        #pragma unroll
        for (int r = 0; r < 4; ++r) {
          int c = cbase + ob * 16 + q4 * 4 + r;
          float bval = (r == 0) ? b4.x : (r == 1) ? b4.y : (r == 2) ? b4.z : b4.w;
          vpan[(size_t)c * 64 + jj] = (_Float16)(acc[ob][nb][r] + bval);
        }
      }
    }
  }
}

// ---------------------------------------------------------------------------
// Kernel 4: fused flash attention + residual -> yout (bf16).
// NT=128 (32 bodies, HALF the previous count), 256 thr (4 waves), M=64,
// grid 512 (2/CU). Body k (uniform, no prologue/epilogue special cases):
//   issue K(k) 8 loads + V(k) 16 loads          (V crosses the barrier)
//   SMAX(k): 8 S-MFMAs -> in-wave max (shfl16/32) -> 32 exp2 -> publish
//            P(k) to LDS buf k&1 (row stride 272B), alpha/flags
//   lgkmcnt(0); s_barrier                        (NO vmcnt drain)
//   rescale (rare, defer-max THR=8) + PV(k): 4 ks x 16 MFMAs, P via
//            ds_read_b128, V from regs (issued ~600cy earlier -> hidden)
// Race safety (one barrier/body, P double-buffered): wave W0 writing
// P(k+1) (buf ~k&1) pre-bar(k+1) never touches buf k&1, and W0 can't
// reach body k+2's writes (buf k&1 again) before bar(k+1), which waits
// for every wave to finish its PV(k) reads. ts-reduce is off the
// critical path (only feeds lrun).
// ---------------------------------------------------------------------------
#define ATTN_BODY(K, BUF) do { \
  /* issue K(K) -- single-buffered, consumed by S below (~300cy stall) */ \
  f16x8 kx_[8]; \
  { const _Float16* kp_ = kbase + (size_t)(K) * 128 * CQK; \
    _Pragma("unroll") \
    for (int jb = 0; jb < 8; ++jb) kx_[jb] = *(const f16x8*)(kp_ + jb * 16 * CQK); } \
  /* issue V(K) -- consumed after the barrier in PV (hidden by SMAX) */ \
  f16x8 vx_[16]; \
  { const _Float16* vp_ = vbase + (size_t)(K) * 2 * VPANEL; \
    _Pragma("unroll") \
    for (int ks = 0; ks < 4; ++ks) \
      _Pragma("unroll") \
      for (int cb = 0; cb < 4; ++cb) \
        vx_[ks * 4 + cb] = *(const f16x8*)(vp_ + (ks >> 1) * VPANEL + cb * 1024 + (ks & 1) * 32); } \
  /* S' = K x Q : 128 j x 16 i; lane holds j = jb*16 + q4*4 + r, i = w*16+l15 */ \
  f32x4 sv_[8]; \
  _Pragma("unroll") \
  for (int jb = 0; jb < 8; ++jb) \
    sv_[jb] = __builtin_amdgcn_mfma_f32_16x16x32_f16(kx_[jb], qfr, zf, 0, 0, 0); \
  float lm_ = sv_[0][0]; \
  _Pragma("unroll") \
  for (int jb = 0; jb < 8; ++jb) \
    lm_ = fmaxf(lm_, fmaxf(fmaxf(sv_[jb][0], sv_[jb][1]), fmaxf(sv_[jb][2], sv_[jb][3]))); \
  lm_ = fmaxf(lm_, __shfl_xor(lm_, 16)); \
  lm_ = fmaxf(lm_, __shfl_xor(lm_, 32)); \
  bool upd_ = lm_ > mold + 8.0f; \
  unsigned long long bal_ = __ballot(upd_);     /* full-wave scope */ \
  float alpha_ = upd_ ? exp2f(mold - lm_) : 1.0f; \
  if (upd_) mold = lm_; \
  float ts_ = 0.f; \
  { char* pb_ = (char*)Plds + (BUF) * 17408 + (w * 16 + l15) * 272 + q4 * 8; \
    _Pragma("unroll") \
    for (int jb = 0; jb < 8; ++jb) { \
      float p0_ = exp2f(sv_[jb][0] - mold), p1_ = exp2f(sv_[jb][1] - mold); \
      float p2_ = exp2f(sv_[jb][2] - mold), p3_ = exp2f(sv_[jb][3] - mold); \
      ts_ += (p0_ + p1_) + (p2_ + p3_); \
      _Float16 h_[4] = {(_Float16)p0_, (_Float16)p1_, (_Float16)p2_, (_Float16)p3_}; \
      *(uint2*)(pb_ + jb * 32) = *(uint2*)h_; } } \
  if (q4 == 0) alphal[(BUF) * 64 + w * 16 + l15] = alpha_; \
  if (lane == 0) flagw[(BUF) * 4 + w] = (bal_ != 0ull) ? 1 : 0; \
  ts_ += __shfl_xor(ts_, 16); \
  ts_ += __shfl_xor(ts_, 32); \
  lrun = lrun * alpha_ + ts_; \
  asm volatile("s_waitcnt lgkmcnt(0)" ::: "memory"); \
  __builtin_amdgcn_sched_barrier(0); \
  __builtin_amdgcn_s_barrier(); \
  asm volatile("" ::: "memory"); \
  /* rescale (rare) */ \
  { int4 fl_ = *(const int4*)(flagw + (BUF) * 4); \
    if (fl_.x | fl_.y | fl_.z | fl_.w) { \
      _Pragma("unroll") \
      for (int ib = 0; ib < 4; ++ib) { \
        float av_ = alphal[(BUF) * 64 + ib * 16 + l15]; \
        _Pragma("unroll") \
        for (int cb = 0; cb < 4; ++cb) \
          _Pragma("unroll") \
          for (int r = 0; r < 4; ++r) acc[cb][ib][r] *= av_; } } } \
  /* PV: O'[c][i] += V x P', 4 ks-slices x 16 MFMAs */ \
  __builtin_amdgcn_s_setprio(1); \
  _Pragma("unroll") \
  for (int ks = 0; ks < 4; ++ks) { \
    f16x8 pf_[4]; \
    _Pragma("unroll") \
    for (int ib = 0; ib < 4; ++ib) \
      pf_[ib] = *(const f16x8*)((char*)Plds + (BUF) * 17408 + (ib * 16 + l15) * 272 + ks * 64 + q4 * 16); \
    _Pragma("unroll") \
    for (int cb = 0; cb < 4; ++cb) \
      _Pragma("unroll") \
      for (int ib = 0; ib < 4; ++ib) \
        acc[cb][ib] = __builtin_amdgcn_mfma_f32_16x16x32_f16(vx_[ks * 4 + cb], pf_[ib], acc[cb][ib], 0, 0, 0); \
  } \
  __builtin_amdgcn_s_setprio(0); \
} while (0)

__global__ __launch_bounds__(256, 2) void attn_kernel(
    const float* __restrict__ x, const float* __restrict__ gptr,
    const _Float16* __restrict__ qf, const _Float16* __restrict__ kf,
    const _Float16* __restrict__ vf, unsigned short* __restrict__ yout)
{
  __shared__ __align__(16) char smem[35648];
  _Float16* Plds  = (_Float16*)smem;             // [2][64 rows][272 B]
  float* alphal = (float*)(smem + 34816);        // [2][64]
  int*   flagw  = (int*)(smem + 35328);          // [2][4]
  float* lrowl  = (float*)(smem + 35360);        // [64]

  const int t = threadIdx.x, lane = t & 63;
  const int w = t >> 6;                           // 4 waves
  const int l15 = lane & 15, q4 = lane >> 4;
  const int b  = blockIdx.x & 7;                  // batch == XCD
  const int it = blockIdx.x >> 3;
  const int i0 = it * 64;
  const float gamma = gptr[0];

  // Q fragment: wave's 16 rows (q pre-scaled by log2 e in proj kernel)
  const f16x8 qfr = *(const f16x8*)(qf + ((size_t)(b * N_) + i0 + w * 16 + l15) * CQK + q4 * 8);

  // per-lane K base: row j = l15 (+16*jb +128*k), k-slice q4*8
  const _Float16* kbase = kf + ((size_t)(b * N_) + l15) * CQK + q4 * 8;
  // per-lane V base (panel-major): c-row = w*64 (+cb*16) + l15, j-chunk q4*8
  const _Float16* vbase = vf + (size_t)b * (64 * VPANEL)
                             + ((size_t)(w * 64 + l15)) * 64 + q4 * 8;

  f32x4 acc[4][4];   // [cb][ib]: c = w*64+cb*16+q4*4+r, i = ib*16+l15
  const f32x4 zf = {0.f, 0.f, 0.f, 0.f};
  #pragma unroll
  for (int a = 0; a < 4; ++a)
    #pragma unroll
    for (int bb = 0; bb < 4; ++bb) acc[a][bb] = zf;

  float mold = -1e30f, lrun = 0.f;

  #pragma unroll 1
  for (int k = 0; k < 32; k += 2) {
    ATTN_BODY(k, 0);
    ATTN_BODY(k + 1, 1);
  }

  if (q4 == 0) lrowl[w * 16 + l15] = lrun;
  __syncthreads();
  #pragma unroll
  for (int ib = 0; ib < 4; ++ib) {
    float linv = 1.0f / lrowl[ib * 16 + l15];
    int i = i0 + ib * 16 + l15;
    #pragma unroll
    for (int cb = 0; cb < 4; ++cb) {
      #pragma unroll
      for (int r = 0; r < 4; ++r) {
        int c = w * 64 + cb * 16 + q4 * 4 + r;
        size_t off = ((size_t)(b * C_) + c) * N_ + i;
        float o = acc[cb][ib][r] * linv;
        yout[off] = f2bf_rne(fmaf(gamma, o, x[off]));
      }
    }
  }
}

// ---------------------------------------------------------------------------
// Kernel 5: BN statistics from bf16 yout; one block per channel.
// ---------------------------------------------------------------------------
__global__ __launch_bounds__(256) void bnstats_kernel(
    const unsigned short* __restrict__ y, float* __restrict__ meanw, float* __restrict__ rstdw)
{
  const int c = blockIdx.x;
  const int t = threadIdx.x;
  float s1 = 0.f, s2 = 0.f;
  for (int b = 0; b < B_; ++b) {
    const unsigned short* p = y + ((size_t)(b * C_ + c)) * N_;
    #pragma unroll
    for (int r = 0; r < 2; ++r) {
      uint4 u = *(const uint4*)(p + r * 2048 + t * 8);
      unsigned uu[4] = {u.x, u.y, u.z, u.w};
      #pragma unroll
      for (int k = 0; k < 4; ++k) {
        float a = __builtin_bit_cast(float, uu[k] << 16);
        float bb = __builtin_bit_cast(float, uu[k] & 0xFFFF0000u);
        s1 += a + bb;
        s2 += a * a + bb * bb;
      }
    }
  }
  __shared__ float r1[256], r2[256];
  r1[t] = s1; r2[t] = s2;
  __syncthreads();
  for (int s = 128; s > 0; s >>= 1) {
    if (t < s) { r1[t] += r1[t + s]; r2[t] += r2[t + s]; }
    __syncthreads();
  }
  if (t == 0) {
    float mean = r1[0] * (1.0f / 32768.0f);
    float var  = r2[0] * (1.0f / 32768.0f) - mean * mean;
    meanw[c] = mean;
    rstdw[c] = rsqrtf(var + 1e-5f);
  }
}

// ---------------------------------------------------------------------------
// Kernel 6: BN normalize + ReLU: bf16 yout -> fp32 d_out.
// ---------------------------------------------------------------------------
__global__ __launch_bounds__(256) void bnapply_kernel(
    const unsigned short* __restrict__ y, float* __restrict__ out,
    const float* __restrict__ meanw, const float* __restrict__ rstdw,
    const float* __restrict__ bnw, const float* __restrict__ bnb)
{
  size_t idx = (size_t)blockIdx.x * 256 + threadIdx.x;   // 1,048,576 threads
  size_t el = idx * 8;
  int c = (int)((el >> 12) & 255);
  float sc = bnw[c] * rstdw[c];
  float sh = fmaf(-meanw[c], sc, bnb[c]);
  uint4 u = *(const uint4*)(y + el);
  unsigned uu[4] = {u.x, u.y, u.z, u.w};
  float4 o0, o1;
  float v[8];
  #pragma unroll
  for (int k = 0; k < 4; ++k) {
    v[2 * k]     = __builtin_bit_cast(float, uu[k] << 16);
    v[2 * k + 1] = __builtin_bit_cast(float, uu[k] & 0xFFFF0000u);
  }
  o0.x = fmaxf(fmaf(v[0], sc, sh), 0.f);
  o0.y = fmaxf(fmaf(v[1], sc, sh), 0.f);
  o0.z = fmaxf(fmaf(v[2], sc, sh), 0.f);
  o0.w = fmaxf(fmaf(v[3], sc, sh), 0.f);
  o1.x = fmaxf(fmaf(v[4], sc, sh), 0.f);
  o1.y = fmaxf(fmaf(v[5], sc, sh), 0.f);
  o1.z = fmaxf(fmaf(v[6], sc, sh), 0.f);
  o1.w = fmaxf(fmaf(v[7], sc, sh), 0.f);
  *(float4*)(out + el) = o0;
  *(float4*)(out + el + 4) = o1;
}

extern "C" void kernel_launch(void* const* d_in, const int* in_sizes, int n_in,
                              void* d_out, int out_size, void* d_ws, size_t ws_size,
                              hipStream_t stream)
{
  const float* x   = (const float*)d_in[0];
  const float* wq  = (const float*)d_in[1];
  const float* bq  = (const float*)d_in[2];
  const float* wk  = (const float*)d_in[3];
  const float* bk  = (const float*)d_in[4];
  const float* wv  = (const float*)d_in[5];
  const float* bv  = (const float*)d_in[6];
  const float* gm  = (const float*)d_in[7];
  const float* bnw = (const float*)d_in[8];
  const float* bnb = (const float*)d_in[9];
  float* out = (float*)d_out;

  // d_out doubles as scratch for xT and v (both dead before bnapply writes):
  //   [0, 16.78 MB)   xT fp16 [b][n][c]
  //   [16.78, 33.55)  v  fp16 PANEL-MAJOR [b][64 jt][256 c][64 j]
  _Float16* xT  = (_Float16*)d_out;
  _Float16* vfp = (_Float16*)((char*)d_out + (size_t)B_ * C_ * N_ * 2);

  // ws: q 2MB | k 2MB | yout bf16 16.78MB | wf 160KB | stats  (~22 MB total)
  char* ws = (char*)d_ws;
  _Float16* qf = (_Float16*)(ws);
  _Float16* kf = (_Float16*)(ws + ((size_t)2 << 20));
  unsigned short* yout = (unsigned short*)(ws + ((size_t)4 << 20));
  _Float16* wf = (_Float16*)(ws + ((size_t)21 << 20));
  float* meanw = (float*)(ws + ((size_t)22 << 20));
  float* rstdw = (float*)(ws + ((size_t)22 << 20) + 4096);

  hipLaunchKernelGGL(xpose_kernel, dim3(1024), dim3(256), 0, stream, x, xT);
  hipLaunchKernelGGL(wconv_kernel, dim3(80), dim3(256), 0, stream, wq, wk, wv, wf);
  hipLaunchKernelGGL(proj_gemm_kernel, dim3(1280), dim3(256), 0, stream,
                     xT, wf, bq, bk, bv, qf, kf, vfp);
  hipLaunchKernelGGL(attn_kernel, dim3(512), dim3(256), 0, stream,
                     x, gm, qf, kf, vfp, yout);
  hipLaunchKernelGGL(bnstats_kernel, dim3(256), dim3(256), 0, stream,
                     yout, meanw, rstdw);
  hipLaunchKernelGGL(bnapply_kernel, dim3(4096), dim3(256), 0, stream,
                     yout, out, meanw, rstdw, bnw, bnb);
}

// Round 7
// 288.874 us; speedup vs baseline: 2.8729x; 1.0309x over previous
//
#include <hip/hip_runtime.h>
#include <stdint.h>

#define B_ 8
#define C_ 256
#define N_ 4096
#define CQK 32
#define VPANEL (C_ * 64)   // f16 elements per 64-key V panel (256 c x 64 j)

typedef __attribute__((ext_vector_type(8))) _Float16 f16x8;
typedef __attribute__((ext_vector_type(4))) float f32x4;

__device__ __forceinline__ unsigned short f2bf_rne(float f) {
  unsigned u = __builtin_bit_cast(unsigned, f);
  u += 0x7FFFu + ((u >> 16) & 1u);
  return (unsigned short)(u >> 16);
}

// ---------------------------------------------------------------------------
// Kernel 2: convert weights to fp16, concatenated Wcat[320][256].
// ---------------------------------------------------------------------------
__global__ __launch_bounds__(256) void wconv_kernel(
    const float* __restrict__ wq, const float* __restrict__ wk,
    const float* __restrict__ wv, _Float16* __restrict__ wf)
{
  int idx = blockIdx.x * 256 + threadIdx.x;   // 20480 threads x 4 elems
  int e = idx * 4;
  int o = e >> 8, c = e & 255;
  const float* src;
  if (o < 32)      src = wq + o * 256 + c;
  else if (o < 64) src = wk + (o - 32) * 256 + c;
  else             src = wv + (o - 64) * 256 + c;
  float4 v = *(const float4*)src;
  _Float16 h[4] = {(_Float16)v.x, (_Float16)v.y, (_Float16)v.z, (_Float16)v.w};
  *(uint2*)(wf + e) = *(uint2*)h;
}

// ---------------------------------------------------------------------------
// FUSED projection: x [b][c][n] fp32 -> (transpose in LDS) -> q/k/v via MFMA.
// Replaces xpose_kernel + proj_gemm_kernel: x is read ONCE (32 MB total,
// vs 128 MB xpose-read + 320 MB xT re-reads before), no xT global round-trip.
// Grid 512 (8 b x 64 n-tiles of 64 px), 256 thr (4 waves). LDS ~49 KB.
// Stage (4 chunks of 64 c):
//   float4-coalesced load -> xs[64][65] fp32 -> column reads (stride 65 dw,
//   bank+1/step: conflict-free; n across lanes: 2-way, free) -> f16x8 ->
//   packed bp[chunk=c/8][n][8] (lane-contiguous 16B: conflict-free write).
// Compute (per otile 0..4): wave = 32o x 32n quadrant, acc[2][2],
//   A-frags from global wf (L2-hot, 160 KB), B-frags ds_read_b128 from bp.
// Outputs identical to previous proj: q (xlog2e) / k row-major [n][32],
//   v PANEL-MAJOR [b][jt=64][c=256][j=64]. attn kernel unchanged.
// ---------------------------------------------------------------------------
__global__ __launch_bounds__(256, 2) void proj_fused_kernel(
    const float* __restrict__ x, const _Float16* __restrict__ wf,
    const float* __restrict__ bq, const float* __restrict__ bk,
    const float* __restrict__ bv,
    _Float16* __restrict__ qf, _Float16* __restrict__ kf,
    _Float16* __restrict__ vout)
{
  __shared__ float xs[64 * 65];            // fp32 stage: one 64c x 64n chunk
  __shared__ _Float16 bp[32 * 64 * 8];     // packed B: [c/8 chunk][n][8c] f16

  const int t = threadIdx.x, lane = t & 63;
  const int w = t >> 6;
  const int l15 = lane & 15, q4 = lane >> 4;
  const int blk = blockIdx.x;
  const int b  = blk & 7;                  // batch == XCD (matches attn)
  const int nt = blk >> 3;                 // 64 n-tiles of 64 px
  const int n0 = nt * 64;
  const int o0w = (w & 1) * 32;            // wave o-offset within 64-row otile
  const int n0w = (w >> 1) * 32;           // wave n-offset within 64-px tile

  // ---- stage x tile: 4 chunks of 64 c ----
  for (int ct = 0; ct < 4; ++ct) {
    #pragma unroll
    for (int p = 0; p < 4; ++p) {
      int cc = p * 16 + (t >> 4);          // 0..63
      int nn = (t & 15) * 4;               // 0..60
      float4 v = *(const float4*)(x + ((size_t)(b * C_) + ct * 64 + cc) * N_ + n0 + nn);
      xs[cc * 65 + nn]     = v.x;
      xs[cc * 65 + nn + 1] = v.y;
      xs[cc * 65 + nn + 2] = v.z;
      xs[cc * 65 + nn + 3] = v.w;
    }
    __syncthreads();
    #pragma unroll
    for (int h = 0; h < 2; ++h) {
      int oct = w + h * 4;                 // 0..7 (c-octet within chunk)
      int n = lane;                        // 0..63
      _Float16 hh[8];
      #pragma unroll
      for (int j = 0; j < 8; ++j) hh[j] = (_Float16)xs[(oct * 8 + j) * 65 + n];
      *(f16x8*)(bp + (((size_t)(ct * 8 + oct)) * 64 + n) * 8) = *(f16x8*)hh;
    }
    __syncthreads();                       // xs reused next ct; bp persists
  }

  // ---- compute all 5 otiles from the staged tile ----
  const f32x4 zf = {0.f, 0.f, 0.f, 0.f};
  for (int otile = 0; otile < 5; ++otile) {
    f32x4 acc[2][2];
    #pragma unroll
    for (int a = 0; a < 2; ++a)
      #pragma unroll
      for (int bb = 0; bb < 2; ++bb) acc[a][bb] = zf;

    const _Float16* wbase = wf + (size_t)(otile * 64 + o0w) * 256;

    #pragma unroll
    for (int kc = 0; kc < 8; ++kc) {
      f16x8 af[2], bfr[2];
      #pragma unroll
      for (int ob = 0; ob < 2; ++ob)
        af[ob] = *(const f16x8*)(wbase + (ob * 16 + l15) * 256 + kc * 32 + q4 * 8);
      #pragma unroll
      for (int nb = 0; nb < 2; ++nb)
        bfr[nb] = *(const f16x8*)(bp + (((size_t)(kc * 4 + q4)) * 64 + n0w + nb * 16 + l15) * 8);
      #pragma unroll
      for (int ob = 0; ob < 2; ++ob)
        #pragma unroll
        for (int nb = 0; nb < 2; ++nb)
          acc[ob][nb] = __builtin_amdgcn_mfma_f32_16x16x32_f16(af[ob], bfr[nb], acc[ob][nb], 0, 0, 0);
    }

    if (otile == 0) {
      _Float16* dst = (o0w == 0) ? qf : kf;
      const float* bias = (o0w == 0) ? bq : bk;
      const float qsc = (o0w == 0) ? 1.4426950408889634f : 1.0f;  // log2(e) for q
      #pragma unroll
      for (int ob = 0; ob < 2; ++ob) {
        float4 b4 = *(const float4*)(bias + ob * 16 + q4 * 4);
        #pragma unroll
        for (int nb = 0; nb < 2; ++nb) {
          int pixel = n0 + n0w + nb * 16 + l15;
          _Float16 h[4];
          h[0] = (_Float16)((acc[ob][nb][0] + b4.x) * qsc);
          h[1] = (_Float16)((acc[ob][nb][1] + b4.y) * qsc);
          h[2] = (_Float16)((acc[ob][nb][2] + b4.z) * qsc);
          h[3] = (_Float16)((acc[ob][nb][3] + b4.w) * qsc);
          *(uint2*)(dst + ((size_t)(b * N_) + pixel) * CQK + ob * 16 + q4 * 4) = *(uint2*)h;
        }
      }
    } else {
      int cbase = (otile - 1) * 64 + o0w;
      _Float16* vpan = vout + ((size_t)(b * 64 + nt)) * VPANEL;
      #pragma unroll
      for (int ob = 0; ob < 2; ++ob) {
        float4 b4 = *(const float4*)(bv + cbase + ob * 16 + q4 * 4);
        #pragma unroll
        for (int nb = 0; nb < 2; ++nb) {
          int jj = n0w + nb * 16 + l15;        // j within panel, 0..63
          #pragma unroll
          for (int r = 0; r < 4; ++r) {
            int c = cbase + ob * 16 + q4 * 4 + r;
            float bval = (r == 0) ? b4.x : (r == 1) ? b4.y : (r == 2) ? b4.z : b4.w;
            vpan[(size_t)c * 64 + jj] = (_Float16)(acc[ob][nb][r] + bval);
          }
        }
      }
    }
  }
}

// ---------------------------------------------------------------------------
// Kernel 4: fused flash attention + residual -> yout (bf16).  (round-6 form,
// unchanged: NT=128, 32 bodies, 4 waves, one lgkm-only raw barrier per body.)
// ---------------------------------------------------------------------------
#define ATTN_BODY(K, BUF) do { \
  f16x8 kx_[8]; \
  { const _Float16* kp_ = kbase + (size_t)(K) * 128 * CQK; \
    _Pragma("unroll") \
    for (int jb = 0; jb < 8; ++jb) kx_[jb] = *(const f16x8*)(kp_ + jb * 16 * CQK); } \
  f16x8 vx_[16]; \
  { const _Float16* vp_ = vbase + (size_t)(K) * 2 * VPANEL; \
    _Pragma("unroll") \
    for (int ks = 0; ks < 4; ++ks) \
      _Pragma("unroll") \
      for (int cb = 0; cb < 4; ++cb) \
        vx_[ks * 4 + cb] = *(const f16x8*)(vp_ + (ks >> 1) * VPANEL + cb * 1024 + (ks & 1) * 32); } \
  f32x4 sv_[8]; \
  _Pragma("unroll") \
  for (int jb = 0; jb < 8; ++jb) \
    sv_[jb] = __builtin_amdgcn_mfma_f32_16x16x32_f16(kx_[jb], qfr, zf, 0, 0, 0); \
  float lm_ = sv_[0][0]; \
  _Pragma("unroll") \
  for (int jb = 0; jb < 8; ++jb) \
    lm_ = fmaxf(lm_, fmaxf(fmaxf(sv_[jb][0], sv_[jb][1]), fmaxf(sv_[jb][2], sv_[jb][3]))); \
  lm_ = fmaxf(lm_, __shfl_xor(lm_, 16)); \
  lm_ = fmaxf(lm_, __shfl_xor(lm_, 32)); \
  bool upd_ = lm_ > mold + 8.0f; \
  unsigned long long bal_ = __ballot(upd_);     /* full-wave scope */ \
  float alpha_ = upd_ ? exp2f(mold - lm_) : 1.0f; \
  if (upd_) mold = lm_; \
  float ts_ = 0.f; \
  { char* pb_ = (char*)Plds + (BUF) * 17408 + (w * 16 + l15) * 272 + q4 * 8; \
    _Pragma("unroll") \
    for (int jb = 0; jb < 8; ++jb) { \
      float p0_ = exp2f(sv_[jb][0] - mold), p1_ = exp2f(sv_[jb][1] - mold); \
      float p2_ = exp2f(sv_[jb][2] - mold), p3_ = exp2f(sv_[jb][3] - mold); \
      ts_ += (p0_ + p1_) + (p2_ + p3_); \
      _Float16 h_[4] = {(_Float16)p0_, (_Float16)p1_, (_Float16)p2_, (_Float16)p3_}; \
      *(uint2*)(pb_ + jb * 32) = *(uint2*)h_; } } \
  if (q4 == 0) alphal[(BUF) * 64 + w * 16 + l15] = alpha_; \
  if (lane == 0) flagw[(BUF) * 4 + w] = (bal_ != 0ull) ? 1 : 0; \
  ts_ += __shfl_xor(ts_, 16); \
  ts_ += __shfl_xor(ts_, 32); \
  lrun = lrun * alpha_ + ts_; \
  asm volatile("s_waitcnt lgkmcnt(0)" ::: "memory"); \
  __builtin_amdgcn_sched_barrier(0); \
  __builtin_amdgcn_s_barrier(); \
  asm volatile("" ::: "memory"); \
  { int4 fl_ = *(const int4*)(flagw + (BUF) * 4); \
    if (fl_.x | fl_.y | fl_.z | fl_.w) { \
      _Pragma("unroll") \
      for (int ib = 0; ib < 4; ++ib) { \
        float av_ = alphal[(BUF) * 64 + ib * 16 + l15]; \
        _Pragma("unroll") \
        for (int cb = 0; cb < 4; ++cb) \
          _Pragma("unroll") \
          for (int r = 0; r < 4; ++r) acc[cb][ib][r] *= av_; } } } \
  __builtin_amdgcn_s_setprio(1); \
  _Pragma("unroll") \
  for (int ks = 0; ks < 4; ++ks) { \
    f16x8 pf_[4]; \
    _Pragma("unroll") \
    for (int ib = 0; ib < 4; ++ib) \
      pf_[ib] = *(const f16x8*)((char*)Plds + (BUF) * 17408 + (ib * 16 + l15) * 272 + ks * 64 + q4 * 16); \
    _Pragma("unroll") \
    for (int cb = 0; cb < 4; ++cb) \
      _Pragma("unroll") \
      for (int ib = 0; ib < 4; ++ib) \
        acc[cb][ib] = __builtin_amdgcn_mfma_f32_16x16x32_f16(vx_[ks * 4 + cb], pf_[ib], acc[cb][ib], 0, 0, 0); \
  } \
  __builtin_amdgcn_s_setprio(0); \
} while (0)

__global__ __launch_bounds__(256, 2) void attn_kernel(
    const float* __restrict__ x, const float* __restrict__ gptr,
    const _Float16* __restrict__ qf, const _Float16* __restrict__ kf,
    const _Float16* __restrict__ vf, unsigned short* __restrict__ yout)
{
  __shared__ __align__(16) char smem[35648];
  _Float16* Plds  = (_Float16*)smem;             // [2][64 rows][272 B]
  float* alphal = (float*)(smem + 34816);        // [2][64]
  int*   flagw  = (int*)(smem + 35328);          // [2][4]
  float* lrowl  = (float*)(smem + 35360);        // [64]

  const int t = threadIdx.x, lane = t & 63;
  const int w = t >> 6;                           // 4 waves
  const int l15 = lane & 15, q4 = lane >> 4;
  const int b  = blockIdx.x & 7;                  // batch == XCD
  const int it = blockIdx.x >> 3;
  const int i0 = it * 64;
  const float gamma = gptr[0];

  const f16x8 qfr = *(const f16x8*)(qf + ((size_t)(b * N_) + i0 + w * 16 + l15) * CQK + q4 * 8);

  const _Float16* kbase = kf + ((size_t)(b * N_) + l15) * CQK + q4 * 8;
  const _Float16* vbase = vf + (size_t)b * (64 * VPANEL)
                             + ((size_t)(w * 64 + l15)) * 64 + q4 * 8;

  f32x4 acc[4][4];   // [cb][ib]: c = w*64+cb*16+q4*4+r, i = ib*16+l15
  const f32x4 zf = {0.f, 0.f, 0.f, 0.f};
  #pragma unroll
  for (int a = 0; a < 4; ++a)
    #pragma unroll
    for (int bb = 0; bb < 4; ++bb) acc[a][bb] = zf;

  float mold = -1e30f, lrun = 0.f;

  #pragma unroll 1
  for (int k = 0; k < 32; k += 2) {
    ATTN_BODY(k, 0);
    ATTN_BODY(k + 1, 1);
  }

  if (q4 == 0) lrowl[w * 16 + l15] = lrun;
  __syncthreads();
  #pragma unroll
  for (int ib = 0; ib < 4; ++ib) {
    float linv = 1.0f / lrowl[ib * 16 + l15];
    int i = i0 + ib * 16 + l15;
    #pragma unroll
    for (int cb = 0; cb < 4; ++cb) {
      #pragma unroll
      for (int r = 0; r < 4; ++r) {
        int c = w * 64 + cb * 16 + q4 * 4 + r;
        size_t off = ((size_t)(b * C_) + c) * N_ + i;
        float o = acc[cb][ib][r] * linv;
        yout[off] = f2bf_rne(fmaf(gamma, o, x[off]));
      }
    }
  }
}

// ---------------------------------------------------------------------------
// Kernel 5: BN statistics from bf16 yout; one block per channel.
// ---------------------------------------------------------------------------
__global__ __launch_bounds__(256) void bnstats_kernel(
    const unsigned short* __restrict__ y, float* __restrict__ meanw, float* __restrict__ rstdw)
{
  const int c = blockIdx.x;
  const int t = threadIdx.x;
  float s1 = 0.f, s2 = 0.f;
  for (int b = 0; b < B_; ++b) {
    const unsigned short* p = y + ((size_t)(b * C_ + c)) * N_;
    #pragma unroll
    for (int r = 0; r < 2; ++r) {
      uint4 u = *(const uint4*)(p + r * 2048 + t * 8);
      unsigned uu[4] = {u.x, u.y, u.z, u.w};
      #pragma unroll
      for (int k = 0; k < 4; ++k) {
        float a = __builtin_bit_cast(float, uu[k] << 16);
        float bb = __builtin_bit_cast(float, uu[k] & 0xFFFF0000u);
        s1 += a + bb;
        s2 += a * a + bb * bb;
      }
    }
  }
  __shared__ float r1[256], r2[256];
  r1[t] = s1; r2[t] = s2;
  __syncthreads();
  for (int s = 128; s > 0; s >>= 1) {
    if (t < s) { r1[t] += r1[t + s]; r2[t] += r2[t + s]; }
    __syncthreads();
  }
  if (t == 0) {
    float mean = r1[0] * (1.0f / 32768.0f);
    float var  = r2[0] * (1.0f / 32768.0f) - mean * mean;
    meanw[c] = mean;
    rstdw[c] = rsqrtf(var + 1e-5f);
  }
}

// ---------------------------------------------------------------------------
// Kernel 6: BN normalize + ReLU: bf16 yout -> fp32 d_out.
// ---------------------------------------------------------------------------
__global__ __launch_bounds__(256) void bnapply_kernel(
    const unsigned short* __restrict__ y, float* __restrict__ out,
    const float* __restrict__ meanw, const float* __restrict__ rstdw,
    const float* __restrict__ bnw, const float* __restrict__ bnb)
{
  size_t idx = (size_t)blockIdx.x * 256 + threadIdx.x;   // 1,048,576 threads
  size_t el = idx * 8;
  int c = (int)((el >> 12) & 255);
  float sc = bnw[c] * rstdw[c];
  float sh = fmaf(-meanw[c], sc, bnb[c]);
  uint4 u = *(const uint4*)(y + el);
  unsigned uu[4] = {u.x, u.y, u.z, u.w};
  float4 o0, o1;
  float v[8];
  #pragma unroll
  for (int k = 0; k < 4; ++k) {
    v[2 * k]     = __builtin_bit_cast(float, uu[k] << 16);
    v[2 * k + 1] = __builtin_bit_cast(float, uu[k] & 0xFFFF0000u);
  }
  o0.x = fmaxf(fmaf(v[0], sc, sh), 0.f);
  o0.y = fmaxf(fmaf(v[1], sc, sh), 0.f);
  o0.z = fmaxf(fmaf(v[2], sc, sh), 0.f);
  o0.w = fmaxf(fmaf(v[3], sc, sh), 0.f);
  o1.x = fmaxf(fmaf(v[4], sc, sh), 0.f);
  o1.y = fmaxf(fmaf(v[5], sc, sh), 0.f);
  o1.z = fmaxf(fmaf(v[6], sc, sh), 0.f);
  o1.w = fmaxf(fmaf(v[7], sc, sh), 0.f);
  *(float4*)(out + el) = o0;
  *(float4*)(out + el + 4) = o1;
}

extern "C" void kernel_launch(void* const* d_in, const int* in_sizes, int n_in,
                              void* d_out, int out_size, void* d_ws, size_t ws_size,
                              hipStream_t stream)
{
  const float* x   = (const float*)d_in[0];
  const float* wq  = (const float*)d_in[1];
  const float* bq  = (const float*)d_in[2];
  const float* wk  = (const float*)d_in[3];
  const float* bk  = (const float*)d_in[4];
  const float* wv  = (const float*)d_in[5];
  const float* bv  = (const float*)d_in[6];
  const float* gm  = (const float*)d_in[7];
  const float* bnw = (const float*)d_in[8];
  const float* bnb = (const float*)d_in[9];
  float* out = (float*)d_out;

  // d_out doubles as scratch for v (dead before bnapply writes):
  //   [16.78, 33.55)  v fp16 PANEL-MAJOR [b][64 jt][256 c][64 j]
  _Float16* vfp = (_Float16*)((char*)d_out + (size_t)B_ * C_ * N_ * 2);

  // ws: q 2MB | k 2MB | yout bf16 16.78MB | wf 160KB | stats  (~22 MB total)
  char* ws = (char*)d_ws;
  _Float16* qf = (_Float16*)(ws);
  _Float16* kf = (_Float16*)(ws + ((size_t)2 << 20));
  unsigned short* yout = (unsigned short*)(ws + ((size_t)4 << 20));
  _Float16* wf = (_Float16*)(ws + ((size_t)21 << 20));
  float* meanw = (float*)(ws + ((size_t)22 << 20));
  float* rstdw = (float*)(ws + ((size_t)22 << 20) + 4096);

  hipLaunchKernelGGL(wconv_kernel, dim3(80), dim3(256), 0, stream, wq, wk, wv, wf);
  hipLaunchKernelGGL(proj_fused_kernel, dim3(512), dim3(256), 0, stream,
                     x, wf, bq, bk, bv, qf, kf, vfp);
  hipLaunchKernelGGL(attn_kernel, dim3(512), dim3(256), 0, stream,
                     x, gm, qf, kf, vfp, yout);
  hipLaunchKernelGGL(bnstats_kernel, dim3(256), dim3(256), 0, stream,
                     yout, meanw, rstdw);
  hipLaunchKernelGGL(bnapply_kernel, dim3(4096), dim3(256), 0, stream,
                     yout, out, meanw, rstdw, bnw, bnb);
}

// Round 8
// 262.829 us; speedup vs baseline: 3.1576x; 1.0991x over previous
//
#include <hip/hip_runtime.h>
#include <stdint.h>

#define B_ 8
#define C_ 256
#define N_ 4096
#define CQK 32
#define VPANEL (C_ * 64)   // f16 elements per 64-key V panel (256 c x 64 j)

typedef __attribute__((ext_vector_type(8))) _Float16 f16x8;
typedef __attribute__((ext_vector_type(4))) float f32x4;

__device__ __forceinline__ unsigned short f2bf_rne(float f) {
  unsigned u = __builtin_bit_cast(unsigned, f);
  u += 0x7FFFu + ((u >> 16) & 1u);
  return (unsigned short)(u >> 16);
}

// raw v_exp_f32: 2^x in ONE instruction (libm exp2f adds a denorm-range
// fixup sequence). Valid here: x <= 8 always; deep-negative flushes to 0.
__device__ __forceinline__ float fexp2(float x) {
  float r; asm("v_exp_f32 %0, %1" : "=v"(r) : "v"(x)); return r;
}

// ---------------------------------------------------------------------------
// Kernel 2: convert weights to fp16, concatenated Wcat[320][256].
// ---------------------------------------------------------------------------
__global__ __launch_bounds__(256) void wconv_kernel(
    const float* __restrict__ wq, const float* __restrict__ wk,
    const float* __restrict__ wv, _Float16* __restrict__ wf)
{
  int idx = blockIdx.x * 256 + threadIdx.x;   // 20480 threads x 4 elems
  int e = idx * 4;
  int o = e >> 8, c = e & 255;
  const float* src;
  if (o < 32)      src = wq + o * 256 + c;
  else if (o < 64) src = wk + (o - 32) * 256 + c;
  else             src = wv + (o - 64) * 256 + c;
  float4 v = *(const float4*)src;
  _Float16 h[4] = {(_Float16)v.x, (_Float16)v.y, (_Float16)v.z, (_Float16)v.w};
  *(uint2*)(wf + e) = *(uint2*)h;
}

// ---------------------------------------------------------------------------
// FUSED projection (round-7, unchanged): x -> LDS transpose -> q/k/v MFMA.
// ---------------------------------------------------------------------------
__global__ __launch_bounds__(256, 2) void proj_fused_kernel(
    const float* __restrict__ x, const _Float16* __restrict__ wf,
    const float* __restrict__ bq, const float* __restrict__ bk,
    const float* __restrict__ bv,
    _Float16* __restrict__ qf, _Float16* __restrict__ kf,
    _Float16* __restrict__ vout)
{
  __shared__ float xs[64 * 65];            // fp32 stage: one 64c x 64n chunk
  __shared__ _Float16 bp[32 * 64 * 8];     // packed B: [c/8 chunk][n][8c] f16

  const int t = threadIdx.x, lane = t & 63;
  const int w = t >> 6;
  const int l15 = lane & 15, q4 = lane >> 4;
  const int blk = blockIdx.x;
  const int b  = blk & 7;                  // batch == XCD (matches attn)
  const int nt = blk >> 3;                 // 64 n-tiles of 64 px
  const int n0 = nt * 64;
  const int o0w = (w & 1) * 32;            // wave o-offset within 64-row otile
  const int n0w = (w >> 1) * 32;           // wave n-offset within 64-px tile

  // ---- stage x tile: 4 chunks of 64 c ----
  for (int ct = 0; ct < 4; ++ct) {
    #pragma unroll
    for (int p = 0; p < 4; ++p) {
      int cc = p * 16 + (t >> 4);          // 0..63
      int nn = (t & 15) * 4;               // 0..60
      float4 v = *(const float4*)(x + ((size_t)(b * C_) + ct * 64 + cc) * N_ + n0 + nn);
      xs[cc * 65 + nn]     = v.x;
      xs[cc * 65 + nn + 1] = v.y;
      xs[cc * 65 + nn + 2] = v.z;
      xs[cc * 65 + nn + 3] = v.w;
    }
    __syncthreads();
    #pragma unroll
    for (int h = 0; h < 2; ++h) {
      int oct = w + h * 4;                 // 0..7 (c-octet within chunk)
      int n = lane;                        // 0..63
      _Float16 hh[8];
      #pragma unroll
      for (int j = 0; j < 8; ++j) hh[j] = (_Float16)xs[(oct * 8 + j) * 65 + n];
      *(f16x8*)(bp + (((size_t)(ct * 8 + oct)) * 64 + n) * 8) = *(f16x8*)hh;
    }
    __syncthreads();                       // xs reused next ct; bp persists
  }

  // ---- compute all 5 otiles from the staged tile ----
  const f32x4 zf = {0.f, 0.f, 0.f, 0.f};
  for (int otile = 0; otile < 5; ++otile) {
    f32x4 acc[2][2];
    #pragma unroll
    for (int a = 0; a < 2; ++a)
      #pragma unroll
      for (int bb = 0; bb < 2; ++bb) acc[a][bb] = zf;

    const _Float16* wbase = wf + (size_t)(otile * 64 + o0w) * 256;

    #pragma unroll
    for (int kc = 0; kc < 8; ++kc) {
      f16x8 af[2], bfr[2];
      #pragma unroll
      for (int ob = 0; ob < 2; ++ob)
        af[ob] = *(const f16x8*)(wbase + (ob * 16 + l15) * 256 + kc * 32 + q4 * 8);
      #pragma unroll
      for (int nb = 0; nb < 2; ++nb)
        bfr[nb] = *(const f16x8*)(bp + (((size_t)(kc * 4 + q4)) * 64 + n0w + nb * 16 + l15) * 8);
      #pragma unroll
      for (int ob = 0; ob < 2; ++ob)
        #pragma unroll
        for (int nb = 0; nb < 2; ++nb)
          acc[ob][nb] = __builtin_amdgcn_mfma_f32_16x16x32_f16(af[ob], bfr[nb], acc[ob][nb], 0, 0, 0);
    }

    if (otile == 0) {
      _Float16* dst = (o0w == 0) ? qf : kf;
      const float* bias = (o0w == 0) ? bq : bk;
      const float qsc = (o0w == 0) ? 1.4426950408889634f : 1.0f;  // log2(e) for q
      #pragma unroll
      for (int ob = 0; ob < 2; ++ob) {
        float4 b4 = *(const float4*)(bias + ob * 16 + q4 * 4);
        #pragma unroll
        for (int nb = 0; nb < 2; ++nb) {
          int pixel = n0 + n0w + nb * 16 + l15;
          _Float16 h[4];
          h[0] = (_Float16)((acc[ob][nb][0] + b4.x) * qsc);
          h[1] = (_Float16)((acc[ob][nb][1] + b4.y) * qsc);
          h[2] = (_Float16)((acc[ob][nb][2] + b4.z) * qsc);
          h[3] = (_Float16)((acc[ob][nb][3] + b4.w) * qsc);
          *(uint2*)(dst + ((size_t)(b * N_) + pixel) * CQK + ob * 16 + q4 * 4) = *(uint2*)h;
        }
      }
    } else {
      int cbase = (otile - 1) * 64 + o0w;
      _Float16* vpan = vout + ((size_t)(b * 64 + nt)) * VPANEL;
      #pragma unroll
      for (int ob = 0; ob < 2; ++ob) {
        float4 b4 = *(const float4*)(bv + cbase + ob * 16 + q4 * 4);
        #pragma unroll
        for (int nb = 0; nb < 2; ++nb) {
          int jj = n0w + nb * 16 + l15;        // j within panel, 0..63
          #pragma unroll
          for (int r = 0; r < 4; ++r) {
            int c = cbase + ob * 16 + q4 * 4 + r;
            float bval = (r == 0) ? b4.x : (r == 1) ? b4.y : (r == 2) ? b4.z : b4.w;
            vpan[(size_t)c * 64 + jj] = (_Float16)(acc[ob][nb][r] + bval);
          }
        }
      }
    }
  }
}

// ---------------------------------------------------------------------------
// Kernel 4: fused flash attention + residual -> yout (bf16).
// Round-7 schedule (NT=128, 32 bodies, 4 waves, 1 lgkm-only barrier/body) +:
//  - K staged in LDS once per block (was loaded 4x, once per wave, from L2):
//    body k ds_writes K(k+1) into buf (k+1)&1 BEFORE bar(k); body k+1 reads
//    it after bar(k); next overwrite of that buf is after bar(k+1). Row pad
//    to 80B (40 f16) -> frag reads <=2-way bank aliasing (free).
//  - raw v_exp_f32 for all exponentials (1 instr vs libm's ~6).
//  - max3-shaped max reduction (31 -> ~20 issued ops).
// ---------------------------------------------------------------------------
#define ATTN_BODY(K, BUF) do { \
  /* staging regs for K(K+1): global loads issued FIRST, ds_write LAST */ \
  f16x8 ks_[2]; \
  { const _Float16* kg_ = kstage + (size_t)(((K) + 1) & 31) * (128 * CQK); \
    _Pragma("unroll") \
    for (int s = 0; s < 2; ++s) { \
      int idx_ = s * 256 + t; \
      ks_[s] = *(const f16x8*)(kg_ + (idx_ >> 2) * CQK + (idx_ & 3) * 8); } } \
  /* V(K) loads -- consumed after the barrier in PV */ \
  f16x8 vx_[16]; \
  { const _Float16* vp_ = vbase + (size_t)(K) * 2 * VPANEL; \
    _Pragma("unroll") \
    for (int ks = 0; ks < 4; ++ks) \
      _Pragma("unroll") \
      for (int cb = 0; cb < 4; ++cb) \
        vx_[ks * 4 + cb] = *(const f16x8*)(vp_ + (ks >> 1) * VPANEL + cb * 1024 + (ks & 1) * 32); } \
  /* K(K) frags from LDS buf K&1 */ \
  f16x8 kx_[8]; \
  { const _Float16* kl_ = Klds + ((K) & 1) * 5120 + l15 * 40 + q4 * 8; \
    _Pragma("unroll") \
    for (int jb = 0; jb < 8; ++jb) kx_[jb] = *(const f16x8*)(kl_ + jb * (16 * 40)); } \
  f32x4 sv_[8]; \
  _Pragma("unroll") \
  for (int jb = 0; jb < 8; ++jb) \
    sv_[jb] = __builtin_amdgcn_mfma_f32_16x16x32_f16(kx_[jb], qfr, zf, 0, 0, 0); \
  float pm_[8]; \
  _Pragma("unroll") \
  for (int jb = 0; jb < 8; ++jb) \
    pm_[jb] = fmaxf(fmaxf(sv_[jb][0], sv_[jb][1]), fmaxf(sv_[jb][2], sv_[jb][3])); \
  float ra_ = fmaxf(fmaxf(pm_[0], pm_[1]), pm_[2]); \
  float rb_ = fmaxf(fmaxf(pm_[3], pm_[4]), pm_[5]); \
  float rc_ = fmaxf(fmaxf(pm_[6], pm_[7]), ra_); \
  float lm_ = fmaxf(rb_, rc_); \
  lm_ = fmaxf(lm_, __shfl_xor(lm_, 16)); \
  lm_ = fmaxf(lm_, __shfl_xor(lm_, 32)); \
  bool upd_ = lm_ > mold + 8.0f; \
  unsigned long long bal_ = __ballot(upd_);     /* full-wave scope */ \
  float alpha_ = upd_ ? fexp2(mold - lm_) : 1.0f; \
  if (upd_) mold = lm_; \
  float ts_ = 0.f; \
  { char* pb_ = (char*)Plds + (BUF) * 17408 + (w * 16 + l15) * 272 + q4 * 8; \
    _Pragma("unroll") \
    for (int jb = 0; jb < 8; ++jb) { \
      float p0_ = fexp2(sv_[jb][0] - mold), p1_ = fexp2(sv_[jb][1] - mold); \
      float p2_ = fexp2(sv_[jb][2] - mold), p3_ = fexp2(sv_[jb][3] - mold); \
      ts_ += (p0_ + p1_) + (p2_ + p3_); \
      _Float16 h_[4] = {(_Float16)p0_, (_Float16)p1_, (_Float16)p2_, (_Float16)p3_}; \
      *(uint2*)(pb_ + jb * 32) = *(uint2*)h_; } } \
  /* write staged K(K+1) into buf (K+1)&1 (pre-barrier) */ \
  { _Float16* kw_ = Klds + (((K) + 1) & 1) * 5120; \
    _Pragma("unroll") \
    for (int s = 0; s < 2; ++s) { \
      int idx_ = s * 256 + t; \
      *(f16x8*)(kw_ + (idx_ >> 2) * 40 + (idx_ & 3) * 8) = ks_[s]; } } \
  if (q4 == 0) alphal[(BUF) * 64 + w * 16 + l15] = alpha_; \
  if (lane == 0) flagw[(BUF) * 4 + w] = (bal_ != 0ull) ? 1 : 0; \
  ts_ += __shfl_xor(ts_, 16); \
  ts_ += __shfl_xor(ts_, 32); \
  lrun = lrun * alpha_ + ts_; \
  asm volatile("s_waitcnt lgkmcnt(0)" ::: "memory"); \
  __builtin_amdgcn_sched_barrier(0); \
  __builtin_amdgcn_s_barrier(); \
  asm volatile("" ::: "memory"); \
  { int4 fl_ = *(const int4*)(flagw + (BUF) * 4); \
    if (fl_.x | fl_.y | fl_.z | fl_.w) { \
      _Pragma("unroll") \
      for (int ib = 0; ib < 4; ++ib) { \
        float av_ = alphal[(BUF) * 64 + ib * 16 + l15]; \
        _Pragma("unroll") \
        for (int cb = 0; cb < 4; ++cb) \
          _Pragma("unroll") \
          for (int r = 0; r < 4; ++r) acc[cb][ib][r] *= av_; } } } \
  __builtin_amdgcn_s_setprio(1); \
  _Pragma("unroll") \
  for (int ks = 0; ks < 4; ++ks) { \
    f16x8 pf_[4]; \
    _Pragma("unroll") \
    for (int ib = 0; ib < 4; ++ib) \
      pf_[ib] = *(const f16x8*)((char*)Plds + (BUF) * 17408 + (ib * 16 + l15) * 272 + ks * 64 + q4 * 16); \
    _Pragma("unroll") \
    for (int cb = 0; cb < 4; ++cb) \
      _Pragma("unroll") \
      for (int ib = 0; ib < 4; ++ib) \
        acc[cb][ib] = __builtin_amdgcn_mfma_f32_16x16x32_f16(vx_[ks * 4 + cb], pf_[ib], acc[cb][ib], 0, 0, 0); \
  } \
  __builtin_amdgcn_s_setprio(0); \
} while (0)

__global__ __launch_bounds__(256, 2) void attn_kernel(
    const float* __restrict__ x, const float* __restrict__ gptr,
    const _Float16* __restrict__ qf, const _Float16* __restrict__ kf,
    const _Float16* __restrict__ vf, unsigned short* __restrict__ yout)
{
  __shared__ __align__(16) char smem[56096];
  _Float16* Plds  = (_Float16*)smem;             // [2][64 rows][272 B]
  _Float16* Klds  = (_Float16*)(smem + 34816);   // [2][128 rows][40 f16 = 80 B]
  float* alphal = (float*)(smem + 55296);        // [2][64]
  int*   flagw  = (int*)(smem + 55808);          // [2][4]
  float* lrowl  = (float*)(smem + 55840);        // [64]

  const int t = threadIdx.x, lane = t & 63;
  const int w = t >> 6;                           // 4 waves
  const int l15 = lane & 15, q4 = lane >> 4;
  const int b  = blockIdx.x & 7;                  // batch == XCD
  const int it = blockIdx.x >> 3;
  const int i0 = it * 64;
  const float gamma = gptr[0];

  const f16x8 qfr = *(const f16x8*)(qf + ((size_t)(b * N_) + i0 + w * 16 + l15) * CQK + q4 * 8);

  // block-level K base (cooperative LDS staging)
  const _Float16* kstage = kf + (size_t)b * N_ * CQK;
  // per-lane V base (panel-major): c-row = w*64 (+cb*16) + l15, j-chunk q4*8
  const _Float16* vbase = vf + (size_t)b * (64 * VPANEL)
                             + ((size_t)(w * 64 + l15)) * 64 + q4 * 8;

  f32x4 acc[4][4];   // [cb][ib]: c = w*64+cb*16+q4*4+r, i = ib*16+l15
  const f32x4 zf = {0.f, 0.f, 0.f, 0.f};
  #pragma unroll
  for (int a = 0; a < 4; ++a)
    #pragma unroll
    for (int bb = 0; bb < 4; ++bb) acc[a][bb] = zf;

  float mold = -1e30f, lrun = 0.f;

  // prologue: stage K(0) into buf 0
  #pragma unroll
  for (int s = 0; s < 2; ++s) {
    int idx = s * 256 + t;
    f16x8 v = *(const f16x8*)(kstage + (idx >> 2) * CQK + (idx & 3) * 8);
    *(f16x8*)(Klds + (idx >> 2) * 40 + (idx & 3) * 8) = v;
  }
  __syncthreads();

  #pragma unroll 1
  for (int k = 0; k < 32; k += 2) {
    ATTN_BODY(k, 0);
    ATTN_BODY(k + 1, 1);
  }

  if (q4 == 0) lrowl[w * 16 + l15] = lrun;
  __syncthreads();
  #pragma unroll
  for (int ib = 0; ib < 4; ++ib) {
    float linv = 1.0f / lrowl[ib * 16 + l15];
    int i = i0 + ib * 16 + l15;
    #pragma unroll
    for (int cb = 0; cb < 4; ++cb) {
      #pragma unroll
      for (int r = 0; r < 4; ++r) {
        int c = w * 64 + cb * 16 + q4 * 4 + r;
        size_t off = ((size_t)(b * C_) + c) * N_ + i;
        float o = acc[cb][ib][r] * linv;
        yout[off] = f2bf_rne(fmaf(gamma, o, x[off]));
      }
    }
  }
}

// ---------------------------------------------------------------------------
// Kernel 5: BN statistics from bf16 yout; one block per channel.
// ---------------------------------------------------------------------------
__global__ __launch_bounds__(256) void bnstats_kernel(
    const unsigned short* __restrict__ y, float* __restrict__ meanw, float* __restrict__ rstdw)
{
  const int c = blockIdx.x;
  const int t = threadIdx.x;
  float s1 = 0.f, s2 = 0.f;
  for (int b = 0; b < B_; ++b) {
    const unsigned short* p = y + ((size_t)(b * C_ + c)) * N_;
    #pragma unroll
    for (int r = 0; r < 2; ++r) {
      uint4 u = *(const uint4*)(p + r * 2048 + t * 8);
      unsigned uu[4] = {u.x, u.y, u.z, u.w};
      #pragma unroll
      for (int k = 0; k < 4; ++k) {
        float a = __builtin_bit_cast(float, uu[k] << 16);
        float bb = __builtin_bit_cast(float, uu[k] & 0xFFFF0000u);
        s1 += a + bb;
        s2 += a * a + bb * bb;
      }
    }
  }
  __shared__ float r1[256], r2[256];
  r1[t] = s1; r2[t] = s2;
  __syncthreads();
  for (int s = 128; s > 0; s >>= 1) {
    if (t < s) { r1[t] += r1[t + s]; r2[t] += r2[t + s]; }
    __syncthreads();
  }
  if (t == 0) {
    float mean = r1[0] * (1.0f / 32768.0f);
    float var  = r2[0] * (1.0f / 32768.0f) - mean * mean;
    meanw[c] = mean;
    rstdw[c] = rsqrtf(var + 1e-5f);
  }
}

// ---------------------------------------------------------------------------
// Kernel 6: BN normalize + ReLU: bf16 yout -> fp32 d_out.
// ---------------------------------------------------------------------------
__global__ __launch_bounds__(256) void bnapply_kernel(
    const unsigned short* __restrict__ y, float* __restrict__ out,
    const float* __restrict__ meanw, const float* __restrict__ rstdw,
    const float* __restrict__ bnw, const float* __restrict__ bnb)
{
  size_t idx = (size_t)blockIdx.x * 256 + threadIdx.x;   // 1,048,576 threads
  size_t el = idx * 8;
  int c = (int)((el >> 12) & 255);
  float sc = bnw[c] * rstdw[c];
  float sh = fmaf(-meanw[c], sc, bnb[c]);
  uint4 u = *(const uint4*)(y + el);
  unsigned uu[4] = {u.x, u.y, u.z, u.w};
  float4 o0, o1;
  float v[8];
  #pragma unroll
  for (int k = 0; k < 4; ++k) {
    v[2 * k]     = __builtin_bit_cast(float, uu[k] << 16);
    v[2 * k + 1] = __builtin_bit_cast(float, uu[k] & 0xFFFF0000u);
  }
  o0.x = fmaxf(fmaf(v[0], sc, sh), 0.f);
  o0.y = fmaxf(fmaf(v[1], sc, sh), 0.f);
  o0.z = fmaxf(fmaf(v[2], sc, sh), 0.f);
  o0.w = fmaxf(fmaf(v[3], sc, sh), 0.f);
  o1.x = fmaxf(fmaf(v[4], sc, sh), 0.f);
  o1.y = fmaxf(fmaf(v[5], sc, sh), 0.f);
  o1.z = fmaxf(fmaf(v[6], sc, sh), 0.f);
  o1.w = fmaxf(fmaf(v[7], sc, sh), 0.f);
  *(float4*)(out + el) = o0;
  *(float4*)(out + el + 4) = o1;
}

extern "C" void kernel_launch(void* const* d_in, const int* in_sizes, int n_in,
                              void* d_out, int out_size, void* d_ws, size_t ws_size,
                              hipStream_t stream)
{
  const float* x   = (const float*)d_in[0];
  const float* wq  = (const float*)d_in[1];
  const float* bq  = (const float*)d_in[2];
  const float* wk  = (const float*)d_in[3];
  const float* bk  = (const float*)d_in[4];
  const float* wv  = (const float*)d_in[5];
  const float* bv  = (const float*)d_in[6];
  const float* gm  = (const float*)d_in[7];
  const float* bnw = (const float*)d_in[8];
  const float* bnb = (const float*)d_in[9];
  float* out = (float*)d_out;

  // d_out doubles as scratch for v (dead before bnapply writes):
  //   [16.78, 33.55)  v fp16 PANEL-MAJOR [b][64 jt][256 c][64 j]
  _Float16* vfp = (_Float16*)((char*)d_out + (size_t)B_ * C_ * N_ * 2);

  // ws: q 2MB | k 2MB | yout bf16 16.78MB | wf 160KB | stats  (~22 MB total)
  char* ws = (char*)d_ws;
  _Float16* qf = (_Float16*)(ws);
  _Float16* kf = (_Float16*)(ws + ((size_t)2 << 20));
  unsigned short* yout = (unsigned short*)(ws + ((size_t)4 << 20));
  _Float16* wf = (_Float16*)(ws + ((size_t)21 << 20));
  float* meanw = (float*)(ws + ((size_t)22 << 20));
  float* rstdw = (float*)(ws + ((size_t)22 << 20) + 4096);

  hipLaunchKernelGGL(wconv_kernel, dim3(80), dim3(256), 0, stream, wq, wk, wv, wf);
  hipLaunchKernelGGL(proj_fused_kernel, dim3(512), dim3(256), 0, stream,
                     x, wf, bq, bk, bv, qf, kf, vfp);
  hipLaunchKernelGGL(attn_kernel, dim3(512), dim3(256), 0, stream,
                     x, gm, qf, kf, vfp, yout);
  hipLaunchKernelGGL(bnstats_kernel, dim3(256), dim3(256), 0, stream,
                     yout, meanw, rstdw);
  hipLaunchKernelGGL(bnapply_kernel, dim3(4096), dim3(256), 0, stream,
                     yout, out, meanw, rstdw, bnw, bnb);
}